// Round 5
// baseline (179.698 us; speedup 1.0000x reference)
//
#include <hip/hip_runtime.h>
#include <math.h>

// SoftVoxelOccupancyVFE: per-voxel masked mean/var of xyz + tiny MLP + sigmoid.
// N=200000 voxels, M=32 points, C=4 channels interleaved.
//
// v5: np-predicated loads — fetch only the bytes the math uses.
//  Post-mortems: v2 (+14us) proved kernel time is visible in dur_us; v4
//  (dense 1KB wave-loads, conflict-free LDS transpose) == v1 (scattered)
//  proved the ~34us kernel share is NOT access-pattern-bound. Remaining
//  lever: bytes demanded. Masked points (p >= np) contribute zero; rows are
//  512B/128B-aligned, a 128B line = 8 points of ONE voxel, so exec-mask
//  predication on (p < np) skips whole lines when np <= 8*line_idx.
//  E[lines/voxel] = E[ceil(np/8)] ~= 2.42 of 4 -> ~63MB instead of 103MB.
//  The predicate replaces the mask multiply (masked lanes hold exact 0).
//  Skeleton otherwise = v1 (best passing 150.9/154.5us): 4 lanes/voxel,
//  8 independent nontemporal loads (issued before accumulation), one
//  2-level shuffle reduction, E[x^2]-mean^2 variance, split MLP.

typedef float floatx4 __attribute__((ext_vector_type(4)));

#define LANES_PER_VOX 4
#define VOX_PER_BLOCK 64   // 256 threads / 4 lanes-per-voxel

__global__ __launch_bounds__(256) void vfe_kernel(
    const floatx4* __restrict__ feats,     // N*32 float4 (x,y,z,w)
    const int*    __restrict__ num_points, // N
    const float*  __restrict__ W1,         // 5x16 row-major
    const float*  __restrict__ b1,         // 16
    const float*  __restrict__ W2,         // 16x1
    const float*  __restrict__ b2,         // 1
    float*        __restrict__ out,        // N
    int N)
{
    __shared__ float sW1[80];
    __shared__ float sb1[16];
    __shared__ float sW2[16];
    __shared__ float sb2;

    const int t = threadIdx.x;
    if (t < 80) sW1[t] = W1[t];
    if (t < 16) { sb1[t] = b1[t]; sW2[t] = W2[t]; }
    if (t == 0) sb2 = b2[0];
    __syncthreads();

    const int j   = t & 3;                 // lane within voxel group (0..3)
    const int vox = blockIdx.x * VOX_PER_BLOCK + (t >> 2);
    if (vox >= N) return;

    const int   np        = num_points[vox];
    const float npf       = (float)np;
    const float inv_denom = 1.0f / fmaxf(npf, 1.0f);

    // Predicated loads: lane j covers points j, j+4, ..., j+28. Loads with
    // p >= np are exec-masked off -> no memory request; a 128B line (8 points
    // of this voxel only) is fetched iff np > 8*line. Loads are issued in a
    // separate unrolled loop so all survivors stay in flight together.
    const floatx4* vbase = feats + (size_t)vox * 32;
    floatx4 f[8];
    #pragma unroll
    for (int i = 0; i < 8; ++i) {
        const int p = j + 4 * i;
        f[i] = (floatx4){0.0f, 0.0f, 0.0f, 0.0f};
        if (p < np)
            f[i] = __builtin_nontemporal_load(&vbase[p]);
    }

    // local partials — no mask multiply needed (masked lanes hold exact 0)
    float sx = 0.0f, sy = 0.0f, sz = 0.0f, sq = 0.0f;
    #pragma unroll
    for (int i = 0; i < 8; ++i) {
        sx += f[i].x;
        sy += f[i].y;
        sz += f[i].z;
        sq += f[i].x * f[i].x + f[i].y * f[i].y + f[i].z * f[i].z;
    }

    // single 2-level reduction over the 4-lane group (xor masks stay in-group)
    #pragma unroll
    for (int d = 1; d <= 2; d <<= 1) {
        sx += __shfl_xor(sx, d);
        sy += __shfl_xor(sy, d);
        sz += __shfl_xor(sz, d);
        sq += __shfl_xor(sq, d);
    }

    const float mean_x = sx * inv_denom;
    const float mean_y = sy * inv_denom;
    const float mean_z = sz * inv_denom;

    // sum (x-mx)^2 over first np pts = sq - (sx^2+sy^2+sz^2)/denom (0 for np=0)
    const float qtot     = sq - (sx * sx + sy * sy + sz * sz) * inv_denom;
    const float var_mean = fmaxf(qtot, 0.0f) * inv_denom * (1.0f / 3.0f);

    const float p_var     = __expf(-0.5f * var_mean);
    const float p_density = fminf(npf, 10.0f) * 0.1f;

    // MLP: lane j computes hidden units j, j+4, j+8, j+12; 2-level reduce
    float c = 0.0f;
    #pragma unroll
    for (int u0 = 0; u0 < 16; u0 += 4) {
        const int u = u0 + j;
        float h = sb1[u]
                + p_density * sW1[u]
                + p_var     * sW1[16 + u]
                + mean_x    * sW1[32 + u]
                + mean_y    * sW1[48 + u]
                + mean_z    * sW1[64 + u];
        c += fmaxf(h, 0.0f) * sW2[u];
    }
    c += __shfl_xor(c, 1);
    c += __shfl_xor(c, 2);

    if (j == 0) {
        const float logit = c + sb2;
        out[vox] = 1.0f / (1.0f + __expf(-logit));
    }
}

extern "C" void kernel_launch(void* const* d_in, const int* in_sizes, int n_in,
                              void* d_out, int out_size, void* d_ws, size_t ws_size,
                              hipStream_t stream) {
    // setup_inputs order: features, num_points, coors, W1, b1, W2, b2
    const floatx4* feats     = (const floatx4*)d_in[0];
    const int*    num_points = (const int*)d_in[1];
    // d_in[2] = coors (unused by the reference)
    const float*  W1 = (const float*)d_in[3];
    const float*  b1 = (const float*)d_in[4];
    const float*  W2 = (const float*)d_in[5];
    const float*  b2 = (const float*)d_in[6];
    float* out = (float*)d_out;

    const int N = in_sizes[1];                 // 200000
    const int blocks = (N + VOX_PER_BLOCK - 1) / VOX_PER_BLOCK;
    vfe_kernel<<<blocks, 256, 0, stream>>>(feats, num_points, W1, b1, W2, b2, out, N);
}

// Round 6
// 150.089 us; speedup vs baseline: 1.1973x; 1.1973x over previous
//
#include <hip/hip_runtime.h>
#include <math.h>

// SoftVoxelOccupancyVFE: per-voxel masked mean/var of xyz + tiny MLP + sigmoid.
// N=200000 voxels, M=32 points, C=4 channels interleaved.
//
// v6: v1 champion skeleton + single-branch byte cut.
//  Session evidence: v4 (dense pattern) == v1 -> pattern-insensitive;
//  v5 (-45% bytes via 8 per-load exec-mask predicates) = +25us -> the
//  serialization tax, not the byte goal, was the failure; v2 (+DS chains)
//  = +14us -> added serial work shows ~1:1. In-CU work accounts for <10us,
//  so kernel sits at ~17-21us ~= the 16.4us fetch floor (103MB @ 6.3TB/s)
//  and dur_us is dominated by ~133us of fixed harness fills/gaps.
//  Remaining lever: demanded bytes, implemented WITHOUT per-load predication:
//   - load points 0..15 unconditionally (dense, no dependency on np),
//   - ONE divergent branch `if (np > 16)` covers the upper two 128B lines
//     (np ~ U{0..32}: skipped by ~52% of voxels -> E[fetch] ~= 372B/512B,
//     ~75MB total). Sector(64B)-optimal for a half split: within each half,
//     any needed np makes all its sectors needed for some lane.
//  Accumulation keeps v1's mask multiplies -> numerics identical to v1.

typedef float floatx4 __attribute__((ext_vector_type(4)));

#define LANES_PER_VOX 4
#define VOX_PER_BLOCK 64   // 256 threads / 4 lanes-per-voxel

__global__ __launch_bounds__(256) void vfe_kernel(
    const floatx4* __restrict__ feats,     // N*32 float4 (x,y,z,w)
    const int*    __restrict__ num_points, // N
    const float*  __restrict__ W1,         // 5x16 row-major
    const float*  __restrict__ b1,         // 16
    const float*  __restrict__ W2,         // 16x1
    const float*  __restrict__ b2,         // 1
    float*        __restrict__ out,        // N
    int N)
{
    __shared__ float sW1[80];
    __shared__ float sb1[16];
    __shared__ float sW2[16];
    __shared__ float sb2;

    const int t = threadIdx.x;
    if (t < 80) sW1[t] = W1[t];
    if (t < 16) { sb1[t] = b1[t]; sW2[t] = W2[t]; }
    if (t == 0) sb2 = b2[0];
    __syncthreads();

    const int j   = t & 3;                 // lane within voxel group (0..3)
    const int vox = blockIdx.x * VOX_PER_BLOCK + (t >> 2);
    if (vox >= N) return;

    const int   np        = num_points[vox];
    const float npf       = (float)np;
    const float inv_denom = 1.0f / fmaxf(npf, 1.0f);

    const floatx4* vbase = feats + (size_t)vox * 32;

    // First half (points 0..15): unconditional dense loads, issued before
    // anything depends on np.
    floatx4 f[8];
    #pragma unroll
    for (int i = 0; i < 4; ++i)
        f[i] = __builtin_nontemporal_load(&vbase[j + 4 * i]);
    #pragma unroll
    for (int i = 4; i < 8; ++i)
        f[i] = (floatx4){0.0f, 0.0f, 0.0f, 0.0f};

    // Second half (points 16..31): one branch per thread; inside, the 4
    // loads are unconditional and batched. Lines 2-3 of this voxel's row
    // are fetched by no other thread -> skipping them cuts HBM traffic.
    if (np > 16) {
        #pragma unroll
        for (int i = 4; i < 8; ++i)
            f[i] = __builtin_nontemporal_load(&vbase[j + 4 * i]);
    }

    // local masked partials (v1 semantics)
    float sx = 0.0f, sy = 0.0f, sz = 0.0f, sq = 0.0f;
    #pragma unroll
    for (int i = 0; i < 8; ++i) {
        const float m = (j + 4 * i < np) ? 1.0f : 0.0f;
        sx += f[i].x * m;
        sy += f[i].y * m;
        sz += f[i].z * m;
        sq += m * (f[i].x * f[i].x + f[i].y * f[i].y + f[i].z * f[i].z);
    }

    // single 2-level reduction over the 4-lane group (xor masks stay in-group)
    #pragma unroll
    for (int d = 1; d <= 2; d <<= 1) {
        sx += __shfl_xor(sx, d);
        sy += __shfl_xor(sy, d);
        sz += __shfl_xor(sz, d);
        sq += __shfl_xor(sq, d);
    }

    const float mean_x = sx * inv_denom;
    const float mean_y = sy * inv_denom;
    const float mean_z = sz * inv_denom;

    // sum m*(x-mx)^2 etc = sq - (sx^2+sy^2+sz^2)/denom  (exact; 0 for np=0)
    const float qtot     = sq - (sx * sx + sy * sy + sz * sz) * inv_denom;
    const float var_mean = fmaxf(qtot, 0.0f) * inv_denom * (1.0f / 3.0f);

    const float p_var     = __expf(-0.5f * var_mean);
    const float p_density = fminf(npf, 10.0f) * 0.1f;

    // MLP: lane j computes hidden units j, j+4, j+8, j+12; 2-level reduce
    float c = 0.0f;
    #pragma unroll
    for (int u0 = 0; u0 < 16; u0 += 4) {
        const int u = u0 + j;
        float h = sb1[u]
                + p_density * sW1[u]
                + p_var     * sW1[16 + u]
                + mean_x    * sW1[32 + u]
                + mean_y    * sW1[48 + u]
                + mean_z    * sW1[64 + u];
        c += fmaxf(h, 0.0f) * sW2[u];
    }
    c += __shfl_xor(c, 1);
    c += __shfl_xor(c, 2);

    if (j == 0) {
        const float logit = c + sb2;
        out[vox] = 1.0f / (1.0f + __expf(-logit));
    }
}

extern "C" void kernel_launch(void* const* d_in, const int* in_sizes, int n_in,
                              void* d_out, int out_size, void* d_ws, size_t ws_size,
                              hipStream_t stream) {
    // setup_inputs order: features, num_points, coors, W1, b1, W2, b2
    const floatx4* feats     = (const floatx4*)d_in[0];
    const int*    num_points = (const int*)d_in[1];
    // d_in[2] = coors (unused by the reference)
    const float*  W1 = (const float*)d_in[3];
    const float*  b1 = (const float*)d_in[4];
    const float*  W2 = (const float*)d_in[5];
    const float*  b2 = (const float*)d_in[6];
    float* out = (float*)d_out;

    const int N = in_sizes[1];                 // 200000
    const int blocks = (N + VOX_PER_BLOCK - 1) / VOX_PER_BLOCK;
    vfe_kernel<<<blocks, 256, 0, stream>>>(feats, num_points, W1, b1, W2, b2, out, N);
}